// Round 6
// baseline (254.569 us; speedup 1.0000x reference)
//
#include <hip/hip_runtime.h>

// KPConv pipeline v8:
//   k_prep: x -> xb bf16  +  Wt transpose (full-line writes).
//   k_agg4: 1 point/wave, 4 pts/block (256 thr), grid 12500.
//           Weights first (frees nb regs), then ALL 32 gathers issued and
//           pinned in flight via sched_barrier(0) (v7's compiler sank them:
//           VGPR=36 proved only ~4 outstanding). launch_bounds(256,5).
//   k_gemm4: NO LDS, NO barriers. 64x128 tile, 4 waves; each wave streams
//           its exclusive A rows + L1/L2-hot Wt directly global->regs,
//           30 fully-unrolled K=32 steps, 8 MFMA each. Waves free-run.

#define NPTS   50000
#define NPAD   50048
#define HNB    32
#define KPTS   15
#define CING   64
#define COUTG  128
#define KDIM   960
#define MSUP   50000
#define INV_EXT 13.888889f

#define X2BF_BLKS 1563  // ceil(50000*64/8/256)
#define WT_BLKS   15    // 960/64
#define TWP       72    // u16 pitch in wt transpose tile

typedef __attribute__((ext_vector_type(8))) short bf16x8;
typedef __attribute__((ext_vector_type(8))) unsigned short u16x8;
typedef __attribute__((ext_vector_type(4))) float f32x4;

static __device__ __forceinline__ unsigned short f2bf(float f) {
    unsigned int u = __float_as_uint(f);
    u += 0x7FFFu + ((u >> 16) & 1u);
    return (unsigned short)(u >> 16);
}

// ---------------- k_prep: x->bf16 + weight transpose ----------------
__global__ __launch_bounds__(256) void kpconv_prep(const float* __restrict__ x,
                                                   unsigned short* __restrict__ xb,
                                                   const float* __restrict__ wgt,
                                                   unsigned short* __restrict__ Wt) {
    __shared__ unsigned short tw[128 * TWP];
    const int tid = threadIdx.x;
    if (blockIdx.x < X2BF_BLKS) {
        int i = (blockIdx.x * 256 + tid) * 8;
        if (i >= MSUP * CING) return;
        float4 a = *(const float4*)(x + i);
        float4 b = *(const float4*)(x + i + 4);
        u16x8 o;
        o[0] = f2bf(a.x); o[1] = f2bf(a.y); o[2] = f2bf(a.z); o[3] = f2bf(a.w);
        o[4] = f2bf(b.x); o[5] = f2bf(b.y); o[6] = f2bf(b.z); o[7] = f2bf(b.w);
        *(u16x8*)(xb + i) = o;
        return;
    }
    const int kc0 = (blockIdx.x - X2BF_BLKS) * 64;
#pragma unroll
    for (int it = 0; it < 32; ++it) {
        int idx = it * 256 + tid;          // kcl*128 + o
        int kcl = idx >> 7, o = idx & 127;
        tw[o * TWP + kcl] = f2bf(wgt[(size_t)(kc0 + kcl) * COUTG + o]);
    }
    __syncthreads();
#pragma unroll
    for (int it = 0; it < 4; ++it) {
        int idx = it * 256 + tid;          // o*8 + c16
        int o = idx >> 3, c16 = idx & 7;
        uint4 v = *(const uint4*)&tw[o * TWP + c16 * 8];
        *(uint4*)&Wt[(size_t)o * KDIM + kc0 + c16 * 8] = v;
    }
}

// ---------------- k_agg4: MFMA aggregate, pinned in-flight gathers ----------------
// Swapped operands:
//   A = gathered x: lane (l15,quad) elem j -> x[nb(h=quad*8+j)][nt*16+l15]
//   B = w:          lane l15 = k,   elem j -> w(h=quad*8+j, k)
//   D[m=quad*4+r][n=l15] = wf[k=l15][c = nt*16 + quad*4 + r]  (c lane-contig)
__global__ __launch_bounds__(256, 5) void kpconv_agg4(
    const float* __restrict__ q_pts, const float* __restrict__ s_pts,
    const int* __restrict__ inds, const unsigned short* __restrict__ xb,
    const float* __restrict__ kpts, unsigned short* __restrict__ wf)
{
    __shared__ float4 nb[4 * HNB];   // 2048 B

    const int tid  = threadIdx.x;
    const int wav  = tid >> 6;
    const int lane = tid & 63;
    const int l15  = lane & 15;
    const int quad = lane >> 4;
    const int n    = blockIdx.x * 4 + wav;

    if (lane < HNB) {
        int m = inds[n * HNB + lane];
        float qx = q_pts[n * 3 + 0];
        float qy = q_pts[n * 3 + 1];
        float qz = q_pts[n * 3 + 2];
        nb[wav * HNB + lane] = make_float4(s_pts[m * 3 + 0] - qx,
                                           s_pts[m * 3 + 1] - qy,
                                           s_pts[m * 3 + 2] - qz,
                                           __int_as_float(m));
    }
    __syncthreads();

    const bool kvalid = (l15 < KPTS);
    const int  kidx   = kvalid ? l15 : 0;
    const float kx = kpts[kidx * 3 + 0];
    const float ky = kpts[kidx * 3 + 1];
    const float kz = kpts[kidx * 3 + 2];

    // weights + row pointers first (nb values die here, freeing regs)
    bf16x8 af;
    const unsigned short* bj[8];
#pragma unroll
    for (int j = 0; j < 8; ++j) {
        float4 v = nb[wav * HNB + quad * 8 + j];
        bj[j] = xb + (((size_t)__float_as_int(v.w)) << 6) + l15;
        float dx = v.x - kx, dy = v.y - ky, dz = v.z - kz;
        float d  = sqrtf(dx * dx + dy * dy + dz * dz);
        float w  = kvalid ? fmaxf(0.f, 1.f - d * INV_EXT) : 0.f;
        af[j] = (short)f2bf(w);
    }

    // issue ALL 32 gathers; fence pins them above any consumer -> 32 in flight
    unsigned int gv[32];
#pragma unroll
    for (int j = 0; j < 8; ++j)
#pragma unroll
        for (int nt = 0; nt < 4; ++nt)
            gv[j * 4 + nt] = bj[j][nt * 16];
    __builtin_amdgcn_sched_barrier(0);

    f32x4 acc[4];
#pragma unroll
    for (int nt = 0; nt < 4; ++nt) acc[nt] = (f32x4){0.f, 0.f, 0.f, 0.f};

#pragma unroll
    for (int nt = 0; nt < 4; ++nt) {
        union { unsigned int u[4]; bf16x8 f; } pk;
#pragma unroll
        for (int jj = 0; jj < 4; ++jj)
            pk.u[jj] = gv[(2 * jj) * 4 + nt] | (gv[(2 * jj + 1) * 4 + nt] << 16);
        acc[nt] = __builtin_amdgcn_mfma_f32_16x16x32_bf16(pk.f, af, acc[nt], 0, 0, 0);
    }

    if (kvalid) {   // lane's k = l15 (k==15 unused; KDIM = 15*64)
        unsigned short* wp = wf + (size_t)n * KDIM + l15 * CING + quad * 4;
#pragma unroll
        for (int nt = 0; nt < 4; ++nt) {
            unsigned int lo = (unsigned)f2bf(acc[nt][0]) | ((unsigned)f2bf(acc[nt][1]) << 16);
            unsigned int hi = (unsigned)f2bf(acc[nt][2]) | ((unsigned)f2bf(acc[nt][3]) << 16);
            *(uint2*)(wp + nt * 16) = make_uint2(lo, hi);
        }
    }
}

// ---------------- k_gemm4: LDS-free streaming GEMM ----------------
// 64x128 tile, 4 waves; wave's A rows are exclusive, Wt is L1/L2-hot ->
// no sharing, no LDS, no barriers. 30 K=32 steps fully unrolled.
//   A-frag: lane (l15,quad): A[wave*16+l15][s*32 + quad*8 ..+8]
//   B-frag: lane (l15,quad): Bt[nf*16+l15][s*32 + quad*8 ..+8]
//   D[m=quad*4+r][n=l15] -> out row blockM+wave*16+quad*4+r, col nf*16+l15
__global__ __launch_bounds__(256, 4) void kpconv_gemm4(
    const unsigned short* __restrict__ A,   // wf [NPAD][960]
    const unsigned short* __restrict__ Bt,  // Wt [128][960]
    const float* __restrict__ bias,
    float* __restrict__ out)
{
    const int tid  = threadIdx.x;
    const int wave = tid >> 6;
    const int lane = tid & 63;
    const int l15  = lane & 15;
    const int quad = lane >> 4;
    const long blockM = (long)blockIdx.x * 64;

    const unsigned short* ap = A + (size_t)(blockM + wave * 16 + l15) * KDIM + quad * 8;
    const unsigned short* bp = Bt + (size_t)l15 * KDIM + quad * 8;

    f32x4 acc[8];
#pragma unroll
    for (int i = 0; i < 8; ++i) acc[i] = (f32x4){0.f, 0.f, 0.f, 0.f};

#pragma unroll
    for (int s = 0; s < 30; ++s) {
        bf16x8 afr = *(const bf16x8*)(ap + s * 32);
#pragma unroll
        for (int nf = 0; nf < 8; ++nf) {
            bf16x8 bfr = *(const bf16x8*)(bp + (size_t)nf * 16 * KDIM + s * 32);
            acc[nf] = __builtin_amdgcn_mfma_f32_16x16x32_bf16(afr, bfr, acc[nf], 0, 0, 0);
        }
    }

    const long r0 = blockM + wave * 16 + quad * 4;
#pragma unroll
    for (int nf = 0; nf < 8; ++nf) {
        const int col = nf * 16 + l15;
        const float bv = bias[col];
#pragma unroll
        for (int r = 0; r < 4; ++r) {
            long row = r0 + r;
            if (row < NPTS) out[row * COUTG + col] = acc[nf][r] + bv;
        }
    }
}

extern "C" void kernel_launch(void* const* d_in, const int* in_sizes, int n_in,
                              void* d_out, int out_size, void* d_ws, size_t ws_size,
                              hipStream_t stream) {
    const float* q_pts = (const float*)d_in[0];
    const float* s_pts = (const float*)d_in[1];
    const int*   inds  = (const int*)d_in[2];
    const float* x     = (const float*)d_in[3];
    const float* kpts  = (const float*)d_in[4];
    const float* wgt   = (const float*)d_in[5];
    const float* bias  = (const float*)d_in[6];
    float* out = (float*)d_out;

    // ws layout: wf [NPAD*960] bf16 | xb [50000*64] bf16 | Wt [128*960] bf16
    unsigned short* wfp = (unsigned short*)d_ws;
    unsigned short* xb  = wfp + (size_t)NPAD * KDIM;
    unsigned short* Wt  = xb + (size_t)MSUP * CING;

    kpconv_prep<<<X2BF_BLKS + WT_BLKS, 256, 0, stream>>>(x, xb, wgt, Wt);
    kpconv_agg4<<<NPTS / 4, 256, 0, stream>>>(q_pts, s_pts, inds, xb, kpts, wfp);
    kpconv_gemm4<<<NPAD / 64, 256, 0, stream>>>(wfp, Wt, bias, out);
}

// Round 7
// 168.282 us; speedup vs baseline: 1.5128x; 1.5128x over previous
//
#include <hip/hip_runtime.h>

// KPConv pipeline v9 — consolidation of proven-best components:
//   k_prep: x -> xb bf16  +  Wt transpose (full-line writes).        (~3us)
//   k_agg4: 1 point/wave, 4 pts/block, grid 12500; all-32-gathers
//           pinned in flight via sched_barrier(0)  (R6 residue: ~48us)
//   k_gemm2: R0's proven 64x128-tile BK=64 register-prefetch GEMM    (~28us)
//           (R6 refuted LDS-free streaming: compiler sinks loads at low
//            VGPR -> serial latency chains, 129us, VALUBusy 1.3%)

#define NPTS   50000
#define NPAD   50048
#define HNB    32
#define KPTS   15
#define CING   64
#define COUTG  128
#define KDIM   960
#define MSUP   50000
#define INV_EXT 13.888889f

#define X2BF_BLKS 1563  // ceil(50000*64/8/256)
#define WT_BLKS   15    // 960/64
#define TWP       72    // u16 pitch in wt transpose tile

typedef __attribute__((ext_vector_type(8))) short bf16x8;
typedef __attribute__((ext_vector_type(8))) unsigned short u16x8;
typedef __attribute__((ext_vector_type(4))) float f32x4;

static __device__ __forceinline__ unsigned short f2bf(float f) {
    unsigned int u = __float_as_uint(f);
    u += 0x7FFFu + ((u >> 16) & 1u);
    return (unsigned short)(u >> 16);
}

// ---------------- k_prep: x->bf16 + weight transpose ----------------
__global__ __launch_bounds__(256) void kpconv_prep(const float* __restrict__ x,
                                                   unsigned short* __restrict__ xb,
                                                   const float* __restrict__ wgt,
                                                   unsigned short* __restrict__ Wt) {
    __shared__ unsigned short tw[128 * TWP];
    const int tid = threadIdx.x;
    if (blockIdx.x < X2BF_BLKS) {
        int i = (blockIdx.x * 256 + tid) * 8;
        if (i >= MSUP * CING) return;
        float4 a = *(const float4*)(x + i);
        float4 b = *(const float4*)(x + i + 4);
        u16x8 o;
        o[0] = f2bf(a.x); o[1] = f2bf(a.y); o[2] = f2bf(a.z); o[3] = f2bf(a.w);
        o[4] = f2bf(b.x); o[5] = f2bf(b.y); o[6] = f2bf(b.z); o[7] = f2bf(b.w);
        *(u16x8*)(xb + i) = o;
        return;
    }
    const int kc0 = (blockIdx.x - X2BF_BLKS) * 64;
#pragma unroll
    for (int it = 0; it < 32; ++it) {
        int idx = it * 256 + tid;          // kcl*128 + o
        int kcl = idx >> 7, o = idx & 127;
        tw[o * TWP + kcl] = f2bf(wgt[(size_t)(kc0 + kcl) * COUTG + o]);
    }
    __syncthreads();
#pragma unroll
    for (int it = 0; it < 4; ++it) {
        int idx = it * 256 + tid;          // o*8 + c16
        int o = idx >> 3, c16 = idx & 7;
        uint4 v = *(const uint4*)&tw[o * TWP + c16 * 8];
        *(uint4*)&Wt[(size_t)o * KDIM + kc0 + c16 * 8] = v;
    }
}

// ---------------- k_agg4: MFMA aggregate, pinned in-flight gathers ----------------
// Swapped operands:
//   A = gathered x: lane (l15,quad) elem j -> x[nb(h=quad*8+j)][nt*16+l15]
//   B = w:          lane l15 = k,   elem j -> w(h=quad*8+j, k)
//   D[m=quad*4+r][n=l15] = wf[k=l15][c = nt*16 + quad*4 + r]  (c lane-contig)
__global__ __launch_bounds__(256, 5) void kpconv_agg4(
    const float* __restrict__ q_pts, const float* __restrict__ s_pts,
    const int* __restrict__ inds, const unsigned short* __restrict__ xb,
    const float* __restrict__ kpts, unsigned short* __restrict__ wf)
{
    __shared__ float4 nb[4 * HNB];   // 2048 B

    const int tid  = threadIdx.x;
    const int wav  = tid >> 6;
    const int lane = tid & 63;
    const int l15  = lane & 15;
    const int quad = lane >> 4;
    const int n    = blockIdx.x * 4 + wav;

    if (lane < HNB) {
        int m = inds[n * HNB + lane];
        float qx = q_pts[n * 3 + 0];
        float qy = q_pts[n * 3 + 1];
        float qz = q_pts[n * 3 + 2];
        nb[wav * HNB + lane] = make_float4(s_pts[m * 3 + 0] - qx,
                                           s_pts[m * 3 + 1] - qy,
                                           s_pts[m * 3 + 2] - qz,
                                           __int_as_float(m));
    }
    __syncthreads();

    const bool kvalid = (l15 < KPTS);
    const int  kidx   = kvalid ? l15 : 0;
    const float kx = kpts[kidx * 3 + 0];
    const float ky = kpts[kidx * 3 + 1];
    const float kz = kpts[kidx * 3 + 2];

    // weights + row pointers first (nb values die here, freeing regs)
    bf16x8 af;
    const unsigned short* bj[8];
#pragma unroll
    for (int j = 0; j < 8; ++j) {
        float4 v = nb[wav * HNB + quad * 8 + j];
        bj[j] = xb + (((size_t)__float_as_int(v.w)) << 6) + l15;
        float dx = v.x - kx, dy = v.y - ky, dz = v.z - kz;
        float d  = sqrtf(dx * dx + dy * dy + dz * dz);
        float w  = kvalid ? fmaxf(0.f, 1.f - d * INV_EXT) : 0.f;
        af[j] = (short)f2bf(w);
    }

    // issue ALL 32 gathers; fence pins them above any consumer -> 32 in flight
    unsigned int gv[32];
#pragma unroll
    for (int j = 0; j < 8; ++j)
#pragma unroll
        for (int nt = 0; nt < 4; ++nt)
            gv[j * 4 + nt] = bj[j][nt * 16];
    __builtin_amdgcn_sched_barrier(0);

    f32x4 acc[4];
#pragma unroll
    for (int nt = 0; nt < 4; ++nt) acc[nt] = (f32x4){0.f, 0.f, 0.f, 0.f};

#pragma unroll
    for (int nt = 0; nt < 4; ++nt) {
        union { unsigned int u[4]; bf16x8 f; } pk;
#pragma unroll
        for (int jj = 0; jj < 4; ++jj)
            pk.u[jj] = gv[(2 * jj) * 4 + nt] | (gv[(2 * jj + 1) * 4 + nt] << 16);
        acc[nt] = __builtin_amdgcn_mfma_f32_16x16x32_bf16(pk.f, af, acc[nt], 0, 0, 0);
    }

    if (kvalid) {   // lane's k = l15 (k==15 unused; KDIM = 15*64)
        unsigned short* wp = wf + (size_t)n * KDIM + l15 * CING + quad * 4;
#pragma unroll
        for (int nt = 0; nt < 4; ++nt) {
            unsigned int lo = (unsigned)f2bf(acc[nt][0]) | ((unsigned)f2bf(acc[nt][1]) << 16);
            unsigned int hi = (unsigned)f2bf(acc[nt][2]) | ((unsigned)f2bf(acc[nt][3]) << 16);
            *(uint2*)(wp + nt * 16) = make_uint2(lo, hi);
        }
    }
}

// ---------------- k_gemm2: R0's proven 64x128 tile, BK=64, reg prefetch ----------------
#define GBM 64
#define GBK 64
#define GLP 72   // LDS pitch elems (144 B: 16B-aligned rows, bank-step 36=4*odd)

__global__ __launch_bounds__(256) void kpconv_gemm2(
    const unsigned short* __restrict__ A,   // wf [NPAD][960]
    const unsigned short* __restrict__ Bt,  // Wt [128][960]
    const float* __restrict__ bias,
    float* __restrict__ out)
{
    __shared__ unsigned short As[GBM * GLP];    // 9216 B
    __shared__ unsigned short Bs[COUTG * GLP];  // 18432 B

    const int tid  = threadIdx.x;
    const int wave = tid >> 6;
    const int lane = tid & 63;
    const int l15  = lane & 15;
    const int quad = lane >> 4;
    const long blockM = (long)blockIdx.x * GBM;

    f32x4 acc[8];
#pragma unroll
    for (int i = 0; i < 8; ++i) acc[i] = (f32x4){0.f, 0.f, 0.f, 0.f};

    // staging: A 64 rows x 64 cols (4 thr/row, 16 elems each -> 2 uint4)
    //          B 128 rows x 64 cols (2 thr/row, 32 elems each -> 4 uint4)
    const int arow = tid >> 2, acol = (tid & 3) * 16;
    const int brow = tid >> 1, bcol = (tid & 1) * 32;
    const unsigned short* aptr = A + (size_t)(blockM + arow) * KDIM + acol;
    const unsigned short* bptr = Bt + (size_t)brow * KDIM + bcol;

    uint4 ra0 = *(const uint4*)(aptr);
    uint4 ra1 = *(const uint4*)(aptr + 8);
    uint4 rb0 = *(const uint4*)(bptr);
    uint4 rb1 = *(const uint4*)(bptr + 8);
    uint4 rb2 = *(const uint4*)(bptr + 16);
    uint4 rb3 = *(const uint4*)(bptr + 24);

    for (int kk = 0; kk < KDIM; kk += GBK) {
        __syncthreads();   // previous iter's frag reads complete
        *(uint4*)&As[arow * GLP + acol]      = ra0;
        *(uint4*)&As[arow * GLP + acol + 8]  = ra1;
        *(uint4*)&Bs[brow * GLP + bcol]      = rb0;
        *(uint4*)&Bs[brow * GLP + bcol + 8]  = rb1;
        *(uint4*)&Bs[brow * GLP + bcol + 16] = rb2;
        *(uint4*)&Bs[brow * GLP + bcol + 24] = rb3;
        __syncthreads();

        if (kk + GBK < KDIM) {   // prefetch next tile into regs (overlaps MFMA)
            ra0 = *(const uint4*)(aptr + kk + GBK);
            ra1 = *(const uint4*)(aptr + kk + GBK + 8);
            rb0 = *(const uint4*)(bptr + kk + GBK);
            rb1 = *(const uint4*)(bptr + kk + GBK + 8);
            rb2 = *(const uint4*)(bptr + kk + GBK + 16);
            rb3 = *(const uint4*)(bptr + kk + GBK + 24);
        }

#pragma unroll
        for (int ch = 0; ch < 2; ++ch) {
            bf16x8 afr = *(bf16x8*)&As[(wave * 16 + l15) * GLP + ch * 32 + quad * 8];
#pragma unroll
            for (int nf = 0; nf < 8; ++nf) {
                bf16x8 bfr = *(bf16x8*)&Bs[(nf * 16 + l15) * GLP + ch * 32 + quad * 8];
                acc[nf] = __builtin_amdgcn_mfma_f32_16x16x32_bf16(afr, bfr, acc[nf], 0, 0, 0);
            }
        }
    }

    const long r0 = blockM + wave * 16 + quad * 4;
#pragma unroll
    for (int nf = 0; nf < 8; ++nf) {
        const int col = nf * 16 + l15;
        const float bv = bias[col];
#pragma unroll
        for (int r = 0; r < 4; ++r) {
            long row = r0 + r;
            if (row < NPTS) out[row * COUTG + col] = acc[nf][r] + bv;
        }
    }
}

extern "C" void kernel_launch(void* const* d_in, const int* in_sizes, int n_in,
                              void* d_out, int out_size, void* d_ws, size_t ws_size,
                              hipStream_t stream) {
    const float* q_pts = (const float*)d_in[0];
    const float* s_pts = (const float*)d_in[1];
    const int*   inds  = (const int*)d_in[2];
    const float* x     = (const float*)d_in[3];
    const float* kpts  = (const float*)d_in[4];
    const float* wgt   = (const float*)d_in[5];
    const float* bias  = (const float*)d_in[6];
    float* out = (float*)d_out;

    // ws layout: wf [NPAD*960] bf16 | xb [50000*64] bf16 | Wt [128*960] bf16
    unsigned short* wfp = (unsigned short*)d_ws;
    unsigned short* xb  = wfp + (size_t)NPAD * KDIM;
    unsigned short* Wt  = xb + (size_t)MSUP * CING;

    kpconv_prep<<<X2BF_BLKS + WT_BLKS, 256, 0, stream>>>(x, xb, wgt, Wt);
    kpconv_agg4<<<NPTS / 4, 256, 0, stream>>>(q_pts, s_pts, inds, xb, kpts, wfp);
    kpconv_gemm2<<<NPAD / GBM, 256, 0, stream>>>(wfp, Wt, bias, out);
}

// Round 8
// 162.946 us; speedup vs baseline: 1.5623x; 1.0327x over previous
//
#include <hip/hip_runtime.h>

// KPConv pipeline v10:
//   k_prep: x -> xb bf16  +  Wt transpose (full-line writes).        (~3us)
//   k_agg5: 1 point/wave, 4 pts/block, grid 12500.
//           Point's full 32x64 bf16 neighbor block staged to LDS via
//           4x global_load_lds(16B) (per-lane gather source, linear LDS
//           dest). DMA queue holds the in-flight state -> immune to the
//           register allocator that defeated v7/v9's reg-prefetch
//           (VGPR=32 proved loads were serialized). 18.9KB LDS ->
//           8 blk/CU = 32 waves/CU.
//   k_gemm2: R0's proven 64x128-tile BK=64 register-prefetch GEMM    (~28us)

#define NPTS   50000
#define NPAD   50048
#define HNB    32
#define KPTS   15
#define CING   64
#define COUTG  128
#define KDIM   960
#define MSUP   50000
#define INV_EXT 13.888889f

#define X2BF_BLKS 1563  // ceil(50000*64/8/256)
#define WT_BLKS   15    // 960/64
#define TWP       72    // u16 pitch in wt transpose tile

typedef __attribute__((ext_vector_type(8))) short bf16x8;
typedef __attribute__((ext_vector_type(8))) unsigned short u16x8;
typedef __attribute__((ext_vector_type(4))) float f32x4;

static __device__ __forceinline__ unsigned short f2bf(float f) {
    unsigned int u = __float_as_uint(f);
    u += 0x7FFFu + ((u >> 16) & 1u);
    return (unsigned short)(u >> 16);
}

static __device__ __forceinline__ void gload_lds16(const unsigned short* g,
                                                   unsigned short* l) {
    __builtin_amdgcn_global_load_lds(
        (const __attribute__((address_space(1))) void*)g,
        (__attribute__((address_space(3))) void*)l, 16, 0, 0);
}

// ---------------- k_prep: x->bf16 + weight transpose ----------------
__global__ __launch_bounds__(256) void kpconv_prep(const float* __restrict__ x,
                                                   unsigned short* __restrict__ xb,
                                                   const float* __restrict__ wgt,
                                                   unsigned short* __restrict__ Wt) {
    __shared__ unsigned short tw[128 * TWP];
    const int tid = threadIdx.x;
    if (blockIdx.x < X2BF_BLKS) {
        int i = (blockIdx.x * 256 + tid) * 8;
        if (i >= MSUP * CING) return;
        float4 a = *(const float4*)(x + i);
        float4 b = *(const float4*)(x + i + 4);
        u16x8 o;
        o[0] = f2bf(a.x); o[1] = f2bf(a.y); o[2] = f2bf(a.z); o[3] = f2bf(a.w);
        o[4] = f2bf(b.x); o[5] = f2bf(b.y); o[6] = f2bf(b.z); o[7] = f2bf(b.w);
        *(u16x8*)(xb + i) = o;
        return;
    }
    const int kc0 = (blockIdx.x - X2BF_BLKS) * 64;
#pragma unroll
    for (int it = 0; it < 32; ++it) {
        int idx = it * 256 + tid;          // kcl*128 + o
        int kcl = idx >> 7, o = idx & 127;
        tw[o * TWP + kcl] = f2bf(wgt[(size_t)(kc0 + kcl) * COUTG + o]);
    }
    __syncthreads();
#pragma unroll
    for (int it = 0; it < 4; ++it) {
        int idx = it * 256 + tid;          // o*8 + c16
        int o = idx >> 3, c16 = idx & 7;
        uint4 v = *(const uint4*)&tw[o * TWP + c16 * 8];
        *(uint4*)&Wt[(size_t)o * KDIM + kc0 + c16 * 8] = v;
    }
}

// ---------------- k_agg5: MFMA aggregate, DMA-staged gathers ----------------
// Swapped operands:
//   A = gathered x: lane (l15,quad) elem j -> x[nb(h=quad*8+j)][nt*16+l15]
//   B = w:          lane l15 = k,   elem j -> w(h=quad*8+j, k)
//   D[m=quad*4+r][n=l15] = wf[k=l15][c = nt*16 + quad*4 + r]  (c lane-contig)
// Staging: DMA i (i=0..3) writes rows i*8..i*8+8 of the wave's 32x64 block:
//   lane L sources xb[m[i*8+(L>>3)]*64 + (L&7)*8 ..+8] -> LDS linear
//   (row L>>3, elems (L&7)*8..+8), i.e. xsw[h*64+c] = x[nb(h)][c].
__global__ __launch_bounds__(256, 8) void kpconv_agg5(
    const float* __restrict__ q_pts, const float* __restrict__ s_pts,
    const int* __restrict__ inds, const unsigned short* __restrict__ xb,
    const float* __restrict__ kpts, unsigned short* __restrict__ wf)
{
    __shared__ float4 nb[4 * HNB];              // 2048 B  (displacements)
    __shared__ int    midx[4 * HNB];            // 512 B   (neighbor indices)
    __shared__ unsigned short xs[4 * HNB * 64]; // 16384 B (gathered features)

    const int tid  = threadIdx.x;
    const int wav  = tid >> 6;
    const int lane = tid & 63;
    const int l15  = lane & 15;
    const int quad = lane >> 4;
    const int n    = blockIdx.x * 4 + wav;

    if (lane < HNB) {
        int m = inds[n * HNB + lane];
        midx[wav * HNB + lane] = m;
        float qx = q_pts[n * 3 + 0];
        float qy = q_pts[n * 3 + 1];
        float qz = q_pts[n * 3 + 2];
        nb[wav * HNB + lane] = make_float4(s_pts[m * 3 + 0] - qx,
                                           s_pts[m * 3 + 1] - qy,
                                           s_pts[m * 3 + 2] - qz,
                                           0.f);
    }
    __syncthreads();

    // ---- issue all 4 DMA stages (4KB in flight, held in LDS-DMA queue) ----
    unsigned short* xsw = &xs[wav * (HNB * 64)];
    {
        const int hsub = lane >> 3;
        const int c0   = (lane & 7) * 8;
#pragma unroll
        for (int i = 0; i < 4; ++i) {
            int m = midx[wav * HNB + i * 8 + hsub];
            gload_lds16(xb + (((size_t)m) << 6) + c0, xsw + i * 8 * 64);
        }
    }

    // ---- distance weights (overlaps DMA latency) ----
    const bool kvalid = (l15 < KPTS);
    const int  kidx   = kvalid ? l15 : 0;
    const float kx = kpts[kidx * 3 + 0];
    const float ky = kpts[kidx * 3 + 1];
    const float kz = kpts[kidx * 3 + 2];

    bf16x8 af;
#pragma unroll
    for (int j = 0; j < 8; ++j) {
        float4 v = nb[wav * HNB + quad * 8 + j];
        float dx = v.x - kx, dy = v.y - ky, dz = v.z - kz;
        float d  = sqrtf(dx * dx + dy * dy + dz * dz);
        float w  = kvalid ? fmaxf(0.f, 1.f - d * INV_EXT) : 0.f;
        af[j] = (short)f2bf(w);
    }

    asm volatile("s_waitcnt vmcnt(0)" ::: "memory");   // DMA complete
    __builtin_amdgcn_sched_barrier(0);

    f32x4 acc[4];
#pragma unroll
    for (int nt = 0; nt < 4; ++nt) acc[nt] = (f32x4){0.f, 0.f, 0.f, 0.f};

#pragma unroll
    for (int nt = 0; nt < 4; ++nt) {
        union { unsigned int u[4]; bf16x8 f; } pk;
#pragma unroll
        for (int jj = 0; jj < 4; ++jj) {
            unsigned int lo = xsw[(quad * 8 + 2 * jj)     * 64 + nt * 16 + l15];
            unsigned int hi = xsw[(quad * 8 + 2 * jj + 1) * 64 + nt * 16 + l15];
            pk.u[jj] = lo | (hi << 16);
        }
        acc[nt] = __builtin_amdgcn_mfma_f32_16x16x32_bf16(pk.f, af, acc[nt], 0, 0, 0);
    }

    if (kvalid) {   // lane's k = l15 (k==15 unused; KDIM = 15*64)
        unsigned short* wp = wf + (size_t)n * KDIM + l15 * CING + quad * 4;
#pragma unroll
        for (int nt = 0; nt < 4; ++nt) {
            unsigned int lo = (unsigned)f2bf(acc[nt][0]) | ((unsigned)f2bf(acc[nt][1]) << 16);
            unsigned int hi = (unsigned)f2bf(acc[nt][2]) | ((unsigned)f2bf(acc[nt][3]) << 16);
            *(uint2*)(wp + nt * 16) = make_uint2(lo, hi);
        }
    }
}

// ---------------- k_gemm2: R0's proven 64x128 tile, BK=64, reg prefetch ----------------
#define GBM 64
#define GBK 64
#define GLP 72   // LDS pitch elems (144 B: 16B-aligned rows, bank-step 36=4*odd)

__global__ __launch_bounds__(256) void kpconv_gemm2(
    const unsigned short* __restrict__ A,   // wf [NPAD][960]
    const unsigned short* __restrict__ Bt,  // Wt [128][960]
    const float* __restrict__ bias,
    float* __restrict__ out)
{
    __shared__ unsigned short As[GBM * GLP];    // 9216 B
    __shared__ unsigned short Bs[COUTG * GLP];  // 18432 B

    const int tid  = threadIdx.x;
    const int wave = tid >> 6;
    const int lane = tid & 63;
    const int l15  = lane & 15;
    const int quad = lane >> 4;
    const long blockM = (long)blockIdx.x * GBM;

    f32x4 acc[8];
#pragma unroll
    for (int i = 0; i < 8; ++i) acc[i] = (f32x4){0.f, 0.f, 0.f, 0.f};

    // staging: A 64 rows x 64 cols (4 thr/row, 16 elems each -> 2 uint4)
    //          B 128 rows x 64 cols (2 thr/row, 32 elems each -> 4 uint4)
    const int arow = tid >> 2, acol = (tid & 3) * 16;
    const int brow = tid >> 1, bcol = (tid & 1) * 32;
    const unsigned short* aptr = A + (size_t)(blockM + arow) * KDIM + acol;
    const unsigned short* bptr = Bt + (size_t)brow * KDIM + bcol;

    uint4 ra0 = *(const uint4*)(aptr);
    uint4 ra1 = *(const uint4*)(aptr + 8);
    uint4 rb0 = *(const uint4*)(bptr);
    uint4 rb1 = *(const uint4*)(bptr + 8);
    uint4 rb2 = *(const uint4*)(bptr + 16);
    uint4 rb3 = *(const uint4*)(bptr + 24);

    for (int kk = 0; kk < KDIM; kk += GBK) {
        __syncthreads();   // previous iter's frag reads complete
        *(uint4*)&As[arow * GLP + acol]      = ra0;
        *(uint4*)&As[arow * GLP + acol + 8]  = ra1;
        *(uint4*)&Bs[brow * GLP + bcol]      = rb0;
        *(uint4*)&Bs[brow * GLP + bcol + 8]  = rb1;
        *(uint4*)&Bs[brow * GLP + bcol + 16] = rb2;
        *(uint4*)&Bs[brow * GLP + bcol + 24] = rb3;
        __syncthreads();

        if (kk + GBK < KDIM) {   // prefetch next tile into regs (overlaps MFMA)
            ra0 = *(const uint4*)(aptr + kk + GBK);
            ra1 = *(const uint4*)(aptr + kk + GBK + 8);
            rb0 = *(const uint4*)(bptr + kk + GBK);
            rb1 = *(const uint4*)(bptr + kk + GBK + 8);
            rb2 = *(const uint4*)(bptr + kk + GBK + 16);
            rb3 = *(const uint4*)(bptr + kk + GBK + 24);
        }

#pragma unroll
        for (int ch = 0; ch < 2; ++ch) {
            bf16x8 afr = *(bf16x8*)&As[(wave * 16 + l15) * GLP + ch * 32 + quad * 8];
#pragma unroll
            for (int nf = 0; nf < 8; ++nf) {
                bf16x8 bfr = *(bf16x8*)&Bs[(nf * 16 + l15) * GLP + ch * 32 + quad * 8];
                acc[nf] = __builtin_amdgcn_mfma_f32_16x16x32_bf16(afr, bfr, acc[nf], 0, 0, 0);
            }
        }
    }

    const long r0 = blockM + wave * 16 + quad * 4;
#pragma unroll
    for (int nf = 0; nf < 8; ++nf) {
        const int col = nf * 16 + l15;
        const float bv = bias[col];
#pragma unroll
        for (int r = 0; r < 4; ++r) {
            long row = r0 + r;
            if (row < NPTS) out[row * COUTG + col] = acc[nf][r] + bv;
        }
    }
}

extern "C" void kernel_launch(void* const* d_in, const int* in_sizes, int n_in,
                              void* d_out, int out_size, void* d_ws, size_t ws_size,
                              hipStream_t stream) {
    const float* q_pts = (const float*)d_in[0];
    const float* s_pts = (const float*)d_in[1];
    const int*   inds  = (const int*)d_in[2];
    const float* x     = (const float*)d_in[3];
    const float* kpts  = (const float*)d_in[4];
    const float* wgt   = (const float*)d_in[5];
    const float* bias  = (const float*)d_in[6];
    float* out = (float*)d_out;

    // ws layout: wf [NPAD*960] bf16 | xb [50000*64] bf16 | Wt [128*960] bf16
    unsigned short* wfp = (unsigned short*)d_ws;
    unsigned short* xb  = wfp + (size_t)NPAD * KDIM;
    unsigned short* Wt  = xb + (size_t)MSUP * CING;

    kpconv_prep<<<X2BF_BLKS + WT_BLKS, 256, 0, stream>>>(x, xb, wgt, Wt);
    kpconv_agg5<<<NPTS / 4, 256, 0, stream>>>(q_pts, s_pts, inds, xb, kpts, wfp);
    kpconv_gemm2<<<NPAD / GBM, 256, 0, stream>>>(wfp, Wt, bias, out);
}